// Round 15
// baseline (1245.767 us; speedup 1.0000x reference)
//
#include <hip/hip_runtime.h>

#define CH     16
#define HID    128
#define HWDIM  128
#define NB     32
#define NSTEPS 32
#define NPIX   (NB * HWDIM * HWDIM)

typedef float    f32x4 __attribute__((ext_vector_type(4)));
typedef _Float16 f16x4 __attribute__((ext_vector_type(4)));
typedef _Float16 f16x8 __attribute__((ext_vector_type(8)));

// compile-time ordering fence: per-wave DS ops complete in order in HW, so
// emission order == correctness for wave-private LDS (round-3+ verified).
#define MEMBAR() asm volatile("" ::: "memory")

// ---------------------------------------------------------------------------
// Prepack weights into per-lane MFMA fragment order (fp16)  (r14 verbatim).
// A/B frag layout (16x16x32): lane l -> row/col = l&15, k = 8*(l>>4)+j.
// ---------------------------------------------------------------------------
__global__ __launch_bounds__(256) void nca_prepack(
    const float* __restrict__ w0, const float* __restrict__ w1,
    _Float16* __restrict__ pw0, _Float16* __restrict__ pw1)
{
    const int tid = threadIdx.x;
    for (int s = tid; s < 16 * 64; s += 256) {
        const int f = s >> 6, l = s & 63;
        const int n = f >> 1, ks = f & 1;
        const int o = 16 * n + (l & 15);
        f16x8 v;
        #pragma unroll
        for (int j = 0; j < 8; ++j) {
            const int k = 32 * ks + 8 * (l >> 4) + j;
            v[j] = (_Float16)(k < 48 ? w0[o * 48 + k] : 0.f);
        }
        *reinterpret_cast<f16x8*>(&pw0[s * 8]) = v;
    }
    for (int s = tid; s < 4 * 64; s += 256) {
        const int ks = s >> 6, l = s & 63;
        f16x8 v;
        #pragma unroll
        for (int j = 0; j < 8; ++j) {
            const int k = 32 * ks + 8 * (l >> 4) + j;
            v[j] = (_Float16)w1[(l & 15) * 128 + k];
        }
        *reinterpret_cast<f16x8*>(&pw1[s * 8]) = v;
    }
}

// ---------------------------------------------------------------------------
// Shared device helpers (math identical to r14's verified core).
// Compact ybuf row: 96 B = y[0..47] f16 (id | dx | dy), 16B-aligned stores;
// K-pad zeros (k=48..63) are materialized in registers, not LDS.
// ---------------------------------------------------------------------------
__device__ __forceinline__ void write_yrow(char* row, const f16x8* yr)
{
    #pragma unroll
    for (int q = 0; q < 6; ++q)
        *reinterpret_cast<f16x8*>(row + 16 * q) = yr[q];
}

__device__ __forceinline__ void load_afrag(const char* slice, int lr, int g,
                                           f16x8* afA, f16x8* afB)
{
    f16x8 z;
    #pragma unroll
    for (int e = 0; e < 8; ++e) z[e] = (_Float16)0.f;
    #pragma unroll
    for (int t = 0; t < 4; ++t) {
        const char* row = slice + (16 * t + lr) * 96;
        afA[t] = *reinterpret_cast<const f16x8*>(row + 16 * g);
        afB[t] = z;                         // k = 48..63 pad (g >= 2)
        if (g < 2)
            afB[t] = *reinterpret_cast<const f16x8*>(row + 64 + 16 * g);
    }
}

// fc0 (H^T = relu(W0*Y^T + b)) + fc1 (d^T += W1*H) over 4 chunks of 32 hidden.
__device__ __forceinline__ void mfma_core(char* slice,
    const f16x8* afA, const f16x8* afB, const f16x8* b1f,
    const _Float16* __restrict__ pw0, const float* __restrict__ fc0_b,
    int l, int lr, int g, f32x4* dacc)
{
    #pragma unroll
    for (int c = 0; c < 4; ++c) {
        f16x8 b0f[4];
        #pragma unroll
        for (int q = 0; q < 4; ++q)
            b0f[q] = *reinterpret_cast<const f16x8*>(&pw0[((4 * c + q) * 64 + l) * 8]);
        const f32x4 bq0 = *reinterpret_cast<const f32x4*>(&fc0_b[32 * c + 4 * g]);
        const f32x4 bq1 = *reinterpret_cast<const f32x4*>(&fc0_b[32 * c + 16 + 4 * g]);
        #pragma unroll
        for (int nl = 0; nl < 2; ++nl) {
            const f32x4 bq = nl ? bq1 : bq0;
            #pragma unroll
            for (int t = 0; t < 4; ++t) {
                f32x4 acc = {0.f, 0.f, 0.f, 0.f};
                acc = __builtin_amdgcn_mfma_f32_16x16x32_f16(b0f[2*nl+0], afA[t], acc, 0, 0, 0);
                acc = __builtin_amdgcn_mfma_f32_16x16x32_f16(b0f[2*nl+1], afB[t], acc, 0, 0, 0);
                // D^T: row = hidden 16nl+4g+r, col = pixel 16t+lr
                f16x4 hv;
                #pragma unroll
                for (int r = 0; r < 4; ++r)
                    hv[r] = (_Float16)fmaxf(acc[r] + bq[r], 0.f);
                *reinterpret_cast<f16x4*>(slice + (16 * t + lr) * 80 + 32 * nl + 8 * g) = hv;
            }
        }
        MEMBAR();        // wave-private in-order DS: writes before reads
        #pragma unroll
        for (int t = 0; t < 4; ++t)
            dacc[t] = __builtin_amdgcn_mfma_f32_16x16x32_f16(
                b1f[c],
                *reinterpret_cast<const f16x8*>(slice + (16 * t + lr) * 80 + 16 * g),
                dacc[t], 0, 0, 0);
        MEMBAR();        // WAR before next chunk's writes
    }
}

// perception from the 20x20 halo (step-s pixels, 18x18 index p)
__device__ __forceinline__ void perceive20(const float* h0, int p,
                                           f16x8* yr, f32x4* xc)
{
    const int ii = p / 18, jj = p - ii * 18;
    const int base = ((ii + 1) * 20 + (jj + 1)) * 20;
    #pragma unroll
    for (int c4 = 0; c4 < 4; ++c4) {
        #define T(dy,dx) (*reinterpret_cast<const f32x4*>(&h0[base + ((dy)*20 + (dx))*20 + 4*c4]))
        const f32x4 n00 = T(-1,-1), n01 = T(-1,0), n02 = T(-1,1);
        const f32x4 n10 = T( 0,-1), n11 = T( 0,0), n12 = T( 0,1);
        const f32x4 n20 = T( 1,-1), n21 = T( 1,0), n22 = T( 1,1);
        #undef T
        const f32x4 sx = ((n02 - n00) + 2.f * (n12 - n10) + (n22 - n20)) * 0.125f;
        const f32x4 sy = ((n20 - n00) + 2.f * (n21 - n01) + (n22 - n02)) * 0.125f;
        xc[c4] = n11;
        #pragma unroll
        for (int e = 0; e < 4; ++e) {
            yr[(c4 >> 1)][(c4 & 1) * 4 + e]     = (_Float16)n11[e];
            yr[2 + (c4 >> 1)][(c4 & 1) * 4 + e] = (_Float16)sx[e];
            yr[4 + (c4 >> 1)][(c4 & 1) * 4 + e] = (_Float16)sy[e];
        }
    }
}

// ---------------------------------------------------------------------------
// Fused double NCA step.  Grid (8,8,32), 3 blocks/CU (LDS 50496; r12-POOL
// proved 3/CU keeps the L2 equilibrium — it breaks only at >=5, r10).
//
// Pool layout (50496 B):
//   P1/P2: halo0 [20][20][20] f32 (32000 B at offset 0) — step s-1 state
//   P2b+:  halo1 [18][18][20] f32 (25920 B at offset 0) — step s state
//          slices at 25920: 4 waves x 6144 B (ybuf 64x96 / hbuf 64x80 /
//          dbuf 64x20 f32), disjoint from halo1
// Step s covers 18x18 = 324 px = 6 groups of 64: wave w owns group w;
// waves 0,1 also own groups 4,5 (pixel ownership keeps ybuf wave-private).
// Step-s results are RMW'd into halo1 (center written by owner thread, d
// added by MFMA lanes, mask_s read with OOB guard so SAME-pad stays zero).
// Step s+1 = r14's verified flow reading halo1; epilogue keeps r9's exact
// global pattern (xin line read paired with xout line store — dummy-consumed).
// ---------------------------------------------------------------------------
template <bool POOL>
__global__ __launch_bounds__(256, 3) void nca_step2(
    const float* __restrict__ xin, float* __restrict__ xout,
    const float* __restrict__ mask0, const float* __restrict__ mask1,
    const _Float16* __restrict__ pw0, const float* __restrict__ fc0_b,
    const _Float16* __restrict__ pw1, float* __restrict__ partial)
{
    __shared__ __align__(16) char pool[50496];
    float* h0 = reinterpret_cast<float*>(pool);   // 20x20, pitch 20 f32
    float* h1 = reinterpret_cast<float*>(pool);   // 18x18, pitch 20 f32

    const int tid = threadIdx.x;
    const int w = tid >> 6, l = tid & 63;
    const int lr = l & 15, g = l >> 4;
    const int bz = blockIdx.z;
    const int y0 = blockIdx.y * 16, x0 = blockIdx.x * 16;

    // ---- P1: stage 20x20 halo0 (zero SAME-pad) ----
    for (int q = tid; q < 20 * 20 * 4; q += 256) {
        const int c4 = q & 3, p = q >> 2;
        const int ii = p / 20, jj = p - ii * 20;
        const int gy = y0 - 2 + ii, gx = x0 - 2 + jj;
        f32x4 v = {0.f, 0.f, 0.f, 0.f};
        if ((unsigned)gy < HWDIM && (unsigned)gx < HWDIM)
            v = *reinterpret_cast<const f32x4*>(
                &xin[(((size_t)bz * HWDIM + gy) * HWDIM + gx) * CH + 4 * c4]);
        *reinterpret_cast<f32x4*>(&h0[p * 20 + 4 * c4]) = v;
    }
    __syncthreads();

    // ---- P2: step-s perception for 324 px into registers ----
    f16x8 yA[6], yB[6];
    f32x4 cA[4], cB[4];
    const bool has2 = tid < (324 - 256);          // threads 0..67 own pixel 256+tid
    perceive20(h0, tid, yA, cA);
    if (has2) perceive20(h0, 256 + tid, yB, cB);
    __syncthreads();     // halo0 dead (halo1 + slices overlay it)

    // ---- P2b: owners write exact f32 centers into halo1 ----
    {
        const int ii = tid / 18, jj = tid - ii * 18;
        #pragma unroll
        for (int q = 0; q < 4; ++q)
            *reinterpret_cast<f32x4*>(&h1[(ii * 18 + jj) * 20 + 4 * q]) = cA[q];
        if (has2) {
            const int p = 256 + tid;
            const int i2 = p / 18, j2 = p - i2 * 18;
            #pragma unroll
            for (int q = 0; q < 4; ++q)
                *reinterpret_cast<f32x4*>(&h1[(i2 * 18 + j2) * 20 + 4 * q]) = cB[q];
        }
    }
    __syncthreads();     // centers visible to all waves

    char* slice = pool + 25920 + w * 6144;        // wave-private scratch

    f16x8 b1f[4];        // W1 frags, reused by both steps
    #pragma unroll
    for (int ks = 0; ks < 4; ++ks)
        b1f[ks] = *reinterpret_cast<const f16x8*>(&pw1[(ks * 64 + l) * 8]);

    // ---- P3: step-s MFMA over 6 groups; d RMW'd into halo1 ----
    const int ngrp = (w < 2) ? 2 : 1;
    #pragma unroll 1
    for (int gi = 0; gi < ngrp; ++gi) {
        const int grp = (gi == 0) ? w : 4 + w;
        if (gi == 0)      write_yrow(slice + l * 96, yA);
        else if (has2)    write_yrow(slice + l * 96, yB);
        MEMBAR();
        f16x8 afA[4], afB[4];
        load_afrag(slice, lr, g, afA, afB);
        MEMBAR();
        f32x4 dacc[4];
        #pragma unroll
        for (int t = 0; t < 4; ++t)
            #pragma unroll
            for (int r = 0; r < 4; ++r) dacc[t][r] = 0.f;
        mfma_core(slice, afA, afB, b1f, pw0, fc0_b, l, lr, g, dacc);
        #pragma unroll
        for (int t = 0; t < 4; ++t) {
            const int p = grp * 64 + 16 * t + lr;
            if (p < 324) {
                const int ii = p / 18, jj = p - ii * 18;
                const int gy = y0 - 1 + ii, gx = x0 - 1 + jj;
                if ((unsigned)gy < HWDIM && (unsigned)gx < HWDIM) {
                    const float m = mask0[((size_t)bz * HWDIM + gy) * HWDIM + gx];
                    f32x4 d4 = dacc[t];
                    if (g == 0) { d4[0] = 0.f; d4[1] = 0.f; d4[2] = 0.f; }  // frozen
                    float* hp = &h1[(ii * 18 + jj) * 20 + 4 * g];
                    f32x4 v = *reinterpret_cast<const f32x4*>(hp);
                    #pragma unroll
                    for (int e = 0; e < 4; ++e) v[e] += d4[e] * m;
                    *reinterpret_cast<f32x4*>(hp) = v;
                }
            }
        }
        MEMBAR();
    }
    __syncthreads();     // halo1 = complete step-s state (OOB pixels = 0)

    // ---- P4: step s+1 on the 16x16 interior (r14 flow, halo = halo1) ----
    const int i = tid >> 4, j = tid & 15;
    f32x4 xc[4];
    {
        const int base = ((i + 1) * 18 + (j + 1)) * 20;
        #pragma unroll
        for (int c4 = 0; c4 < 4; ++c4) {
            #define T(dy,dx) (*reinterpret_cast<const f32x4*>(&h1[base + ((dy)*18 + (dx))*20 + 4*c4]))
            const f32x4 n00 = T(-1,-1), n01 = T(-1,0), n02 = T(-1,1);
            const f32x4 n10 = T( 0,-1), n11 = T( 0,0), n12 = T( 0,1);
            const f32x4 n20 = T( 1,-1), n21 = T( 1,0), n22 = T( 1,1);
            #undef T
            const f32x4 sx = ((n02 - n00) + 2.f * (n12 - n10) + (n22 - n20)) * 0.125f;
            const f32x4 sy = ((n20 - n00) + 2.f * (n21 - n01) + (n22 - n02)) * 0.125f;
            xc[c4] = n11;
            #pragma unroll
            for (int e = 0; e < 4; ++e) {
                yA[(c4 >> 1)][(c4 & 1) * 4 + e]     = (_Float16)n11[e];
                yA[2 + (c4 >> 1)][(c4 & 1) * 4 + e] = (_Float16)sx[e];
                yA[4 + (c4 >> 1)][(c4 & 1) * 4 + e] = (_Float16)sy[e];
            }
        }
    }
    // no barrier needed: slices are disjoint from halo1
    write_yrow(slice + l * 96, yA);
    MEMBAR();
    f16x8 afA[4], afB[4];
    load_afrag(slice, lr, g, afA, afB);
    MEMBAR();
    f32x4 dacc[4];
    #pragma unroll
    for (int t = 0; t < 4; ++t)
        #pragma unroll
        for (int r = 0; r < 4; ++r) dacc[t][r] = 0.f;
    mfma_core(slice, afA, afB, b1f, pw0, fc0_b, l, lr, g, dacc);

    float* db = reinterpret_cast<float*>(slice);  // [64 px][20] f32
    #pragma unroll
    for (int t = 0; t < 4; ++t)
        *reinterpret_cast<f32x4*>(&db[(16 * t + lr) * 20 + 4 * g]) = dacc[t];
    MEMBAR();

    // ---- epilogue: r9-exact global pattern (xin line read + xout store) ----
    f32x4 ov[4];
    {
        const size_t pix = ((size_t)bz * HWDIM + (y0 + i)) * HWDIM + (x0 + j);
        const float m = mask1[pix];
        const float* dp = db + l * 20;
        const f32x4* xi4 = reinterpret_cast<const f32x4*>(&xin[pix * CH]);
        f32x4* xo4 = reinterpret_cast<f32x4*>(&xout[pix * CH]);
        #pragma unroll
        for (int q = 0; q < 4; ++q) {
            f32x4 stale = xi4[q];                 // read-before-write pairing
            asm volatile("" :: "v"(stale[0]));    // keep the load alive
            const f32x4 d4 = *reinterpret_cast<const f32x4*>(&dp[4 * q]);
            f32x4 v = xc[q];
            #pragma unroll
            for (int e = 0; e < 4; ++e) v[e] += d4[e] * m;
            if (q == 0) { v[0] = xc[0][0]; v[1] = xc[0][1]; v[2] = xc[0][2]; }  // frozen
            xo4[q] = v;
            ov[q] = v;
        }
    }

    // ---- POOL (last pair): block-reduce channel sums -> partial ----
    if (POOL) {
        __syncthreads();     // all halo1/slice reads done before overlay
        float* red = reinterpret_cast<float*>(pool);          // [256][16]
        #pragma unroll
        for (int q = 0; q < 4; ++q)
            *reinterpret_cast<f32x4*>(&red[tid * CH + 4 * q]) = ov[q];
        __syncthreads();
        for (int off = 128; off > 0; off >>= 1) {
            if (tid < off) {
                #pragma unroll
                for (int c = 0; c < CH; ++c)
                    red[tid * CH + c] += red[(tid + off) * CH + c];
            }
            __syncthreads();
        }
        if (tid < CH) {
            const int tile = (bz * 8 + blockIdx.y) * 8 + blockIdx.x;
            partial[tile * CH + tid] = red[tid];
        }
    }
}

// ---------------------------------------------------------------------------
// Classifier head, one block per batch: sum 64 tile-partials -> fc2 -> fc3.
// ---------------------------------------------------------------------------
__global__ __launch_bounds__(128) void nca_head(
    const float* __restrict__ partial,
    const float* __restrict__ fc2_w, const float* __restrict__ fc2_b,
    const float* __restrict__ fc3_w, const float* __restrict__ fc3_b,
    float* __restrict__ out)
{
    __shared__ float h2[HID];
    __shared__ float pl[CH];
    const int tid = threadIdx.x, b = blockIdx.x;
    if (tid < CH) {
        float s = 0.f;
        #pragma unroll
        for (int q = 0; q < 64; ++q) s += partial[(b * 64 + q) * CH + tid];
        pl[tid] = s * (1.f / (HWDIM * HWDIM));
    }
    __syncthreads();
    float h = fc2_b[tid];
    #pragma unroll
    for (int c = 0; c < CH; ++c) h += fc2_w[tid * CH + c] * pl[c];
    h2[tid] = fmaxf(h, 0.f);
    __syncthreads();
    if (tid < 13) {
        float o = fc3_b[tid];
        #pragma unroll
        for (int jj = 0; jj < HID; ++jj) o += fc3_w[tid * HID + jj] * h2[jj];
        out[b * 13 + tid] = o;
    }
}

// ---------------------------------------------------------------------------
extern "C" void kernel_launch(void* const* d_in, const int* in_sizes, int n_in,
                              void* d_out, int out_size, void* d_ws, size_t ws_size,
                              hipStream_t stream)
{
    const float* x     = (const float*)d_in[0];
    const float* masks = (const float*)d_in[1];
    const float* fc0_w = (const float*)d_in[2];
    const float* fc0_b = (const float*)d_in[3];
    const float* fc1_w = (const float*)d_in[4];
    const float* fc2_w = (const float*)d_in[5];
    const float* fc2_b = (const float*)d_in[6];
    const float* fc3_w = (const float*)d_in[7];
    const float* fc3_b = (const float*)d_in[8];

    float*    out     = (float*)d_out;
    float*    xf      = out + NB * 13;                             // output 1 region
    float*    buf0    = (float*)d_ws;                              // ping-pong state
    float*    partial = buf0 + (size_t)NPIX * CH / (HWDIM * HWDIM) * HWDIM * HWDIM; // = buf0 + NPIX*CH? keep simple below
    partial           = buf0 + (size_t)NB * HWDIM * HWDIM * CH;    // 2048*16 f
    _Float16* pw0     = (_Float16*)(partial + 2048 * CH);          // 16 KiB
    _Float16* pw1     = pw0 + 16 * 64 * 8;                         // 4 KiB

    nca_prepack<<<1, 256, 0, stream>>>(fc0_w, fc1_w, pw0, pw1);

    dim3 grid(HWDIM / 16, HWDIM / 16, NB), block(256);
    // pair k computes steps 2k (18x18, in LDS) and 2k+1 (16x16, to HBM)
    for (int k = 0; k < NSTEPS / 2; ++k) {
        const float* in = (k == 0) ? x : ((k & 1) ? buf0 : xf);
        float* outp     = (k & 1) ? xf : buf0;                     // k=15 -> xf
        const float* m0 = masks + (size_t)(2 * k) * NPIX;
        const float* m1 = masks + (size_t)(2 * k + 1) * NPIX;
        if (k == NSTEPS / 2 - 1)
            nca_step2<true><<<grid, block, 0, stream>>>(in, outp, m0, m1, pw0, fc0_b, pw1, partial);
        else
            nca_step2<false><<<grid, block, 0, stream>>>(in, outp, m0, m1, pw0, fc0_b, pw1, partial);
    }
    nca_head<<<NB, 128, 0, stream>>>(partial, fc2_w, fc2_b, fc3_w, fc3_b, out);
}

// Round 16
// 1171.740 us; speedup vs baseline: 1.0632x; 1.0632x over previous
//
#include <hip/hip_runtime.h>

#define CH     16
#define HID    128
#define HWDIM  128
#define NB     32
#define NSTEPS 32

typedef float    f32x4 __attribute__((ext_vector_type(4)));
typedef _Float16 f16x4 __attribute__((ext_vector_type(4)));
typedef _Float16 f16x8 __attribute__((ext_vector_type(8)));

// compile-time ordering fence: per-wave DS ops complete in order in HW, so
// emission order == correctness for wave-private LDS (round-3+ verified).
#define MEMBAR() asm volatile("" ::: "memory")

// ---------------------------------------------------------------------------
// Prepack weights into per-lane MFMA fragment order (fp16).
// A/B frag layout (16x16x32): lane l -> row/col = l&15, k = 8*(l>>4)+j.
// pw0 (A-operand W0): 16 frags, f = n*2+ks (n = hidden 16-tile, K pad 48->64)
// pw1 (A-operand W1): 4 frags,  f = ks (K over 128)
// ---------------------------------------------------------------------------
__global__ __launch_bounds__(256) void nca_prepack(
    const float* __restrict__ w0, const float* __restrict__ w1,
    _Float16* __restrict__ pw0, _Float16* __restrict__ pw1)
{
    const int tid = threadIdx.x;
    for (int s = tid; s < 16 * 64; s += 256) {
        const int f = s >> 6, l = s & 63;
        const int n = f >> 1, ks = f & 1;
        const int o = 16 * n + (l & 15);
        f16x8 v;
        #pragma unroll
        for (int j = 0; j < 8; ++j) {
            const int k = 32 * ks + 8 * (l >> 4) + j;
            v[j] = (_Float16)(k < 48 ? w0[o * 48 + k] : 0.f);
        }
        *reinterpret_cast<f16x8*>(&pw0[s * 8]) = v;
    }
    for (int s = tid; s < 4 * 64; s += 256) {
        const int ks = s >> 6, l = s & 63;
        f16x8 v;
        #pragma unroll
        for (int j = 0; j < 8; ++j) {
            const int k = 32 * ks + 8 * (l >> 4) + j;
            v[j] = (_Float16)w1[(l & 15) * 128 + k];
        }
        *reinterpret_cast<f16x8*>(&pw1[s * 8]) = v;
    }
}

// ---------------------------------------------------------------------------
// One NCA step — r14 shell (measured best: 890 us, WRITE 32768 KB exact)
// + two in-equilibrium latency micro-fixes:
//   (a) all 16 W0 fragments preloaded to VGPRs before the chunk loop
//   (b) mask load hoisted above the MFMA phase (hides ~300cy under compute)
//
// CACHE EQUILIBRIUM RULES (measured r3/r9/r11/r12/r14 vs r5-r8/r10/r13/r15):
//   (1) exactly 4 blocks/CU (LDS 36864 + launch_bounds(256,4)); >=5 thrashes
//       per-XCD L2 (FETCH 23->100 MB, WRITE 33->185 MB, r10).
//   (2) grid (8,8,32): block->XCD affinity constant across steps.
//   (3) epilogue reads xin[pix] full-width AND USES the value as the store
//       base; r15's dummy-consumed (compiler-narrowed) read still amplified.
//   (4) per-step launches, NOT cooperative (r13: grid.sync fences, 6.7x).
//   (5) no multi-step fusion: the 20x20 halo footprint at 3 blocks/CU broke
//       the equilibrium (r15: FETCH 73 MB, WRITE 105 MB per pair).
//
// LDS pool 36864 B: phase A halo f32 [18][18][20] (cross-wave, 2 barriers);
//   phase B per-wave 9216 B slices: ybuf[64][144 B] -> hbuf[64][80 B]
//   -> dbuf[64][20 f32]  (wave-private, MEMBAR ordering only).
// POOL=true (step 31): block-reduce channel sums -> partial[tile][16];
// redbuf OVERLAYS dead wave slices (extra barrier) so LDS stays 36864.
// ---------------------------------------------------------------------------
template <bool POOL>
__global__ __launch_bounds__(256, 4) void nca_step(
    const float* __restrict__ xin, float* __restrict__ xout,
    const float* __restrict__ mask,
    const _Float16* __restrict__ pw0, const float* __restrict__ fc0_b,
    const _Float16* __restrict__ pw1, float* __restrict__ partial)
{
    __shared__ __align__(16) char pool[36864];
    float (*halo)[18][20] = reinterpret_cast<float(*)[18][20]>(pool);

    const int tid = threadIdx.x;
    const int w = tid >> 6, l = tid & 63;
    const int lr = l & 15, g = l >> 4;
    const int bz = blockIdx.z;
    const int y0 = blockIdx.y * 16, x0 = blockIdx.x * 16;

    // ---- stage halo, pixel-major f32, pitch 20 floats (bank-safe) ----
    for (int q = tid; q < 18 * 18 * 4; q += 256) {
        const int c4 = q & 3, p = q >> 2;
        const int ii = p / 18, jj = p - ii * 18;
        const int gy = y0 - 1 + ii, gx = x0 - 1 + jj;
        f32x4 v = {0.f, 0.f, 0.f, 0.f};
        if ((unsigned)gy < HWDIM && (unsigned)gx < HWDIM)
            v = *reinterpret_cast<const f32x4*>(
                &xin[(((size_t)bz * HWDIM + gy) * HWDIM + gx) * CH + 4 * c4]);
        *reinterpret_cast<f32x4*>(&halo[ii][jj][4 * c4]) = v;
    }
    __syncthreads();     // halo staged

    // ---- perception (f32, shared 9-tap loads), results as f16 in regs ----
    const int j = tid & 15, i = tid >> 4;
    const int li = i + 1, lj = j + 1;
    _Float16 idv[16], dxv[16], dyv[16];
    #pragma unroll
    for (int c4 = 0; c4 < 4; ++c4) {
        #define HLD(dy, dx) (*reinterpret_cast<const f32x4*>(&halo[li + (dy)][lj + (dx)][4 * c4]))
        const f32x4 n00 = HLD(-1,-1), n01 = HLD(-1,0), n02 = HLD(-1,1);
        const f32x4 n10 = HLD( 0,-1), n11 = HLD( 0,0), n12 = HLD( 0,1);
        const f32x4 n20 = HLD( 1,-1), n21 = HLD( 1,0), n22 = HLD( 1,1);
        #undef HLD
        const f32x4 gx = ((n02 - n00) + 2.f * (n12 - n10) + (n22 - n20)) * 0.125f;
        const f32x4 gy = ((n20 - n00) + 2.f * (n21 - n01) + (n22 - n02)) * 0.125f;
        #pragma unroll
        for (int e = 0; e < 4; ++e) {
            idv[4 * c4 + e] = (_Float16)n11[e];
            dxv[4 * c4 + e] = (_Float16)gx[e];
            dyv[4 * c4 + e] = (_Float16)gy[e];
        }
    }

    // ---- (b) hoisted mask load: hides under the whole MFMA phase ----
    const size_t pix = ((size_t)bz * HWDIM + (y0 + i)) * HWDIM + (x0 + j);
    const float m = mask[pix];

    __syncthreads();     // ALL waves' halo reads done before ybuf clobbers halo

    char* wreg = pool + w * 9216;          // this wave's private slice

    // ---- ybuf write: own row l, pitch 144 B; cols 0..47 = y, 48..63 = 0 ----
    {
        _Float16* yrow = reinterpret_cast<_Float16*>(wreg + l * 144);
        f16x8 v;
        #pragma unroll
        for (int e = 0; e < 8; ++e) v[e] = idv[e];
        *reinterpret_cast<f16x8*>(&yrow[0]) = v;
        #pragma unroll
        for (int e = 0; e < 8; ++e) v[e] = idv[8 + e];
        *reinterpret_cast<f16x8*>(&yrow[8]) = v;
        #pragma unroll
        for (int e = 0; e < 8; ++e) v[e] = dxv[e];
        *reinterpret_cast<f16x8*>(&yrow[16]) = v;
        #pragma unroll
        for (int e = 0; e < 8; ++e) v[e] = dxv[8 + e];
        *reinterpret_cast<f16x8*>(&yrow[24]) = v;
        #pragma unroll
        for (int e = 0; e < 8; ++e) v[e] = dyv[e];
        *reinterpret_cast<f16x8*>(&yrow[32]) = v;
        #pragma unroll
        for (int e = 0; e < 8; ++e) v[e] = dyv[8 + e];
        *reinterpret_cast<f16x8*>(&yrow[40]) = v;
        f16x8 z;
        #pragma unroll
        for (int e = 0; e < 8; ++e) z[e] = (_Float16)0.f;
        *reinterpret_cast<f16x8*>(&yrow[48]) = z;   // K-pad 48..63 = 0
        *reinterpret_cast<f16x8*>(&yrow[56]) = z;
    }
    MEMBAR();

    // ---- Y fragments (MFMA B operand: col = pixel 16t+lr, k = 8g+j) ----
    f16x8 afrag[8];
    #pragma unroll
    for (int t = 0; t < 4; ++t)
        #pragma unroll
        for (int ks = 0; ks < 2; ++ks)
            afrag[2 * t + ks] = *reinterpret_cast<const f16x8*>(
                wreg + (16 * t + lr) * 144 + 64 * ks + 16 * g);
    MEMBAR();

    // ---- W1 fragments + (a) ALL W0 fragments preloaded to VGPRs ----
    f16x8 b1f[4];
    #pragma unroll
    for (int ks = 0; ks < 4; ++ks)
        b1f[ks] = *reinterpret_cast<const f16x8*>(&pw1[(ks * 64 + l) * 8]);
    f16x8 b0f[16];
    #pragma unroll
    for (int q = 0; q < 16; ++q)
        b0f[q] = *reinterpret_cast<const f16x8*>(&pw0[(q * 64 + l) * 8]);

    f32x4 dacc[4];
    #pragma unroll
    for (int t = 0; t < 4; ++t)
        #pragma unroll
        for (int r = 0; r < 4; ++r) dacc[t][r] = 0.f;

    // ---- 4 chunks of 32 hidden: H^T = relu(W0*Y^T + b), d^T += W1*H ----
    _Float16* hb = reinterpret_cast<_Float16*>(wreg);   // [64 px][80 B] f16
    #pragma unroll
    for (int c = 0; c < 4; ++c) {
        const f32x4 bq0 = *reinterpret_cast<const f32x4*>(&fc0_b[32 * c + 4 * g]);
        const f32x4 bq1 = *reinterpret_cast<const f32x4*>(&fc0_b[32 * c + 16 + 4 * g]);
        #pragma unroll
        for (int nl = 0; nl < 2; ++nl) {
            const f32x4 bq = nl ? bq1 : bq0;
            #pragma unroll
            for (int t = 0; t < 4; ++t) {
                f32x4 acc = {0.f, 0.f, 0.f, 0.f};
                acc = __builtin_amdgcn_mfma_f32_16x16x32_f16(b0f[4*c + 2*nl + 0], afrag[2*t+0], acc, 0, 0, 0);
                acc = __builtin_amdgcn_mfma_f32_16x16x32_f16(b0f[4*c + 2*nl + 1], afrag[2*t+1], acc, 0, 0, 0);
                // D^T: row = hidden 16nl+4g+r, col = pixel 16t+lr
                f16x4 hv;
                #pragma unroll
                for (int r = 0; r < 4; ++r)
                    hv[r] = (_Float16)fmaxf(acc[r] + bq[r], 0.f);
                *reinterpret_cast<f16x4*>(
                    reinterpret_cast<char*>(hb) + (16 * t + lr) * 80 + 32 * nl + 8 * g) = hv;
            }
        }
        MEMBAR();        // wave-private in-order DS: writes before reads
        #pragma unroll
        for (int t = 0; t < 4; ++t)
            dacc[t] = __builtin_amdgcn_mfma_f32_16x16x32_f16(
                b1f[c],
                *reinterpret_cast<const f16x8*>(
                    reinterpret_cast<const char*>(hb) + (16 * t + lr) * 80 + 16 * g),
                dacc[t], 0, 0, 0);
        MEMBAR();        // WAR before next chunk's writes
    }

    // ---- transpose d to thread-pixel layout: 4 ds_write_b128 per lane ----
    float* db = reinterpret_cast<float*>(wreg);         // [64 px][20] f32
    #pragma unroll
    for (int t = 0; t < 4; ++t)
        *reinterpret_cast<f32x4*>(&db[(16 * t + lr) * 20 + 4 * g]) = dacc[t];
    MEMBAR();

    // ---- epilogue: xin re-read + paired store (equilibrium rule (3)) ----
    f32x4 ov[4];
    {
        const float* dp = db + l * 20;
        const f32x4* xi4 = reinterpret_cast<const f32x4*>(&xin[pix * CH]);
        f32x4* xo4 = reinterpret_cast<f32x4*>(&xout[pix * CH]);
        const f32x4 dv = *reinterpret_cast<const f32x4*>(&dp[0]);
        f32x4 v0 = xi4[0];                  // ch 0..2 frozen (exact copy)
        v0[3] += dv[3] * m;
        xo4[0] = v0;
        ov[0] = v0;
        #pragma unroll
        for (int q = 1; q < 4; ++q) {
            const f32x4 d4 = *reinterpret_cast<const f32x4*>(&dp[4 * q]);
            f32x4 v = xi4[q];
            #pragma unroll
            for (int e = 0; e < 4; ++e) v[e] += d4[e] * m;
            xo4[q] = v;
            ov[q] = v;
        }
    }

    // ---- POOL (step 31 only): block-reduce channel sums -> partial;
    //      redbuf overlays the dead wave slices, LDS stays 36864 ----
    if (POOL) {
        __syncthreads();     // all waves' db reads done before redbuf overlay
        float* red = reinterpret_cast<float*>(pool);           // [256][16]
        #pragma unroll
        for (int q = 0; q < 4; ++q)
            *reinterpret_cast<f32x4*>(&red[tid * CH + 4 * q]) = ov[q];
        __syncthreads();
        for (int off = 128; off > 0; off >>= 1) {
            if (tid < off) {
                #pragma unroll
                for (int c = 0; c < CH; ++c)
                    red[tid * CH + c] += red[(tid + off) * CH + c];
            }
            __syncthreads();
        }
        if (tid < CH) {
            const int tile = (bz * 8 + blockIdx.y) * 8 + blockIdx.x;
            partial[tile * CH + tid] = red[tid];
        }
    }
}

// ---------------------------------------------------------------------------
// Classifier head, one block per batch: sum 64 tile-partials -> fc2 -> fc3.
// ---------------------------------------------------------------------------
__global__ __launch_bounds__(128) void nca_head(
    const float* __restrict__ partial,
    const float* __restrict__ fc2_w, const float* __restrict__ fc2_b,
    const float* __restrict__ fc3_w, const float* __restrict__ fc3_b,
    float* __restrict__ out)
{
    __shared__ float h2[HID];
    __shared__ float pl[CH];
    const int tid = threadIdx.x, b = blockIdx.x;
    if (tid < CH) {
        float s = 0.f;
        #pragma unroll
        for (int q = 0; q < 64; ++q) s += partial[(b * 64 + q) * CH + tid];
        pl[tid] = s * (1.f / (HWDIM * HWDIM));
    }
    __syncthreads();
    float h = fc2_b[tid];
    #pragma unroll
    for (int c = 0; c < CH; ++c) h += fc2_w[tid * CH + c] * pl[c];
    h2[tid] = fmaxf(h, 0.f);
    __syncthreads();
    if (tid < 13) {
        float o = fc3_b[tid];
        #pragma unroll
        for (int jj = 0; jj < HID; ++jj) o += fc3_w[tid * HID + jj] * h2[jj];
        out[b * 13 + tid] = o;
    }
}

// ---------------------------------------------------------------------------
extern "C" void kernel_launch(void* const* d_in, const int* in_sizes, int n_in,
                              void* d_out, int out_size, void* d_ws, size_t ws_size,
                              hipStream_t stream)
{
    const float* x     = (const float*)d_in[0];
    const float* masks = (const float*)d_in[1];
    const float* fc0_w = (const float*)d_in[2];
    const float* fc0_b = (const float*)d_in[3];
    const float* fc1_w = (const float*)d_in[4];
    const float* fc2_w = (const float*)d_in[5];
    const float* fc2_b = (const float*)d_in[6];
    const float* fc3_w = (const float*)d_in[7];
    const float* fc3_b = (const float*)d_in[8];

    float*    out     = (float*)d_out;
    float*    xf      = out + NB * 13;                             // output 1 region
    float*    buf0    = (float*)d_ws;                              // ping-pong state
    float*    partial = buf0 + (size_t)NB * HWDIM * HWDIM * CH;    // 2048*16 f
    _Float16* pw0     = (_Float16*)(partial + 2048 * CH);          // 16 KiB
    _Float16* pw1     = pw0 + 16 * 64 * 8;                         // 4 KiB

    nca_prepack<<<1, 256, 0, stream>>>(fc0_w, fc1_w, pw0, pw1);

    dim3 grid(HWDIM / 16, HWDIM / 16, NB), block(256);
    for (int s = 0; s < NSTEPS; ++s) {
        const float* in = (s == 0) ? x : ((s & 1) ? buf0 : xf);
        float* outp     = (s & 1) ? xf : buf0;
        const float* mk = masks + (size_t)s * NB * HWDIM * HWDIM;
        if (s == NSTEPS - 1)
            nca_step<true><<<grid, block, 0, stream>>>(in, outp, mk, pw0, fc0_b, pw1, partial);
        else
            nca_step<false><<<grid, block, 0, stream>>>(in, outp, mk, pw0, fc0_b, pw1, partial);
    }
    nca_head<<<NB, 128, 0, stream>>>(partial, fc2_w, fc2_b, fc3_w, fc3_b, out);
}

// Round 17
// 890.360 us; speedup vs baseline: 1.3992x; 1.3160x over previous
//
#include <hip/hip_runtime.h>

#define CH     16
#define HID    128
#define HWDIM  128
#define NB     32
#define NSTEPS 32

typedef float    f32x4 __attribute__((ext_vector_type(4)));
typedef _Float16 f16x4 __attribute__((ext_vector_type(4)));
typedef _Float16 f16x8 __attribute__((ext_vector_type(8)));

// compile-time ordering fence: per-wave DS ops complete in order in HW, so
// emission order == correctness for wave-private LDS (round-3+ verified).
#define MEMBAR() asm volatile("" ::: "memory")

// ---------------------------------------------------------------------------
// Prepack weights into per-lane MFMA fragment order (fp16).
// A/B frag layout (16x16x32): lane l -> row/col = l&15, k = 8*(l>>4)+j.
// pw0 (A-operand W0): 16 frags, f = n*2+ks (n = hidden 16-tile, K pad 48->64)
// pw1 (A-operand W1): 4 frags,  f = ks (K over 128)
// ---------------------------------------------------------------------------
__global__ __launch_bounds__(256) void nca_prepack(
    const float* __restrict__ w0, const float* __restrict__ w1,
    _Float16* __restrict__ pw0, _Float16* __restrict__ pw1)
{
    const int tid = threadIdx.x;
    for (int s = tid; s < 16 * 64; s += 256) {
        const int f = s >> 6, l = s & 63;
        const int n = f >> 1, ks = f & 1;
        const int o = 16 * n + (l & 15);
        f16x8 v;
        #pragma unroll
        for (int j = 0; j < 8; ++j) {
            const int k = 32 * ks + 8 * (l >> 4) + j;
            v[j] = (_Float16)(k < 48 ? w0[o * 48 + k] : 0.f);
        }
        *reinterpret_cast<f16x8*>(&pw0[s * 8]) = v;
    }
    for (int s = tid; s < 4 * 64; s += 256) {
        const int ks = s >> 6, l = s & 63;
        f16x8 v;
        #pragma unroll
        for (int j = 0; j < 8; ++j) {
            const int k = 32 * ks + 8 * (l >> 4) + j;
            v[j] = (_Float16)w1[(l & 15) * 128 + k];
        }
        *reinterpret_cast<f16x8*>(&pw1[s * 8]) = v;
    }
}

// ---------------------------------------------------------------------------
// One NCA step — the consolidated best configuration (r14, 890 us measured).
//
// CACHE EQUILIBRIUM RULES (measured across 16 rounds; violations in
// parentheses each inflated HBM traffic 2-3x and regressed):
//   (1) exactly 4 blocks/CU: LDS 36864 + launch_bounds(256,4)
//       (r10: 6 blocks/CU -> FETCH 23->100 MB, WRITE 33->185 MB).
//   (2) grid (8,8,32): block->XCD affinity constant across steps; inter-step
//       L2 retention gives FETCH 23.4 MB < 33.5 MB input.
//   (3) epilogue: mask load + xin[pix] full-width re-read IMMEDIATELY paired
//       with each xout[pix] store, in the epilogue (r5/r6/r8: removing the
//       re-read -> 2.2-3.5x WRITE; r16: merely hoisting the mask load out of
//       the epilogue -> FETCH 53 MB, WRITE 72 MB).
//   (4) per-step launches, NOT cooperative (r13: grid.sync fences, 6.7x).
//   (5) no multi-step fusion (r15: 20x20 halo at 3 blocks/CU -> FETCH 73,
//       WRITE 105 MB per pair).
//   (6) no intra-kernel load rescheduling beyond this layout (r16).
// Perception via ybuf round-trip beats fragment-direct by ~3 us (r11).
//
// LDS pool 36864 B: phase A halo f32 [18][18][20] (cross-wave, 2 barriers);
//   phase B per-wave 9216 B slices: ybuf[64][144 B] -> hbuf[64][80 B]
//   -> dbuf[64][20 f32]  (wave-private, MEMBAR ordering only).
// POOL=true (step 31): block-reduce channel sums -> partial[tile][16];
// redbuf OVERLAYS dead wave slices (extra barrier) so LDS stays 36864.
// ---------------------------------------------------------------------------
template <bool POOL>
__global__ __launch_bounds__(256, 4) void nca_step(
    const float* __restrict__ xin, float* __restrict__ xout,
    const float* __restrict__ mask,
    const _Float16* __restrict__ pw0, const float* __restrict__ fc0_b,
    const _Float16* __restrict__ pw1, float* __restrict__ partial)
{
    __shared__ __align__(16) char pool[36864];
    float (*halo)[18][20] = reinterpret_cast<float(*)[18][20]>(pool);

    const int tid = threadIdx.x;
    const int w = tid >> 6, l = tid & 63;
    const int lr = l & 15, g = l >> 4;
    const int bz = blockIdx.z;
    const int y0 = blockIdx.y * 16, x0 = blockIdx.x * 16;

    // ---- stage halo, pixel-major f32, pitch 20 floats (bank-safe) ----
    for (int q = tid; q < 18 * 18 * 4; q += 256) {
        const int c4 = q & 3, p = q >> 2;
        const int ii = p / 18, jj = p - ii * 18;
        const int gy = y0 - 1 + ii, gx = x0 - 1 + jj;
        f32x4 v = {0.f, 0.f, 0.f, 0.f};
        if ((unsigned)gy < HWDIM && (unsigned)gx < HWDIM)
            v = *reinterpret_cast<const f32x4*>(
                &xin[(((size_t)bz * HWDIM + gy) * HWDIM + gx) * CH + 4 * c4]);
        *reinterpret_cast<f32x4*>(&halo[ii][jj][4 * c4]) = v;
    }
    __syncthreads();     // halo staged

    // ---- perception (f32, shared 9-tap loads), results as f16 in regs ----
    const int j = tid & 15, i = tid >> 4;
    const int li = i + 1, lj = j + 1;
    _Float16 idv[16], dxv[16], dyv[16];
    #pragma unroll
    for (int c4 = 0; c4 < 4; ++c4) {
        #define HLD(dy, dx) (*reinterpret_cast<const f32x4*>(&halo[li + (dy)][lj + (dx)][4 * c4]))
        const f32x4 n00 = HLD(-1,-1), n01 = HLD(-1,0), n02 = HLD(-1,1);
        const f32x4 n10 = HLD( 0,-1), n11 = HLD( 0,0), n12 = HLD( 0,1);
        const f32x4 n20 = HLD( 1,-1), n21 = HLD( 1,0), n22 = HLD( 1,1);
        #undef HLD
        const f32x4 gx = ((n02 - n00) + 2.f * (n12 - n10) + (n22 - n20)) * 0.125f;
        const f32x4 gy = ((n20 - n00) + 2.f * (n21 - n01) + (n22 - n02)) * 0.125f;
        #pragma unroll
        for (int e = 0; e < 4; ++e) {
            idv[4 * c4 + e] = (_Float16)n11[e];
            dxv[4 * c4 + e] = (_Float16)gx[e];
            dyv[4 * c4 + e] = (_Float16)gy[e];
        }
    }
    __syncthreads();     // ALL waves' halo reads done before ybuf clobbers halo

    char* wreg = pool + w * 9216;          // this wave's private slice

    // ---- ybuf write: own row l, pitch 144 B; cols 0..47 = y, 48..63 = 0 ----
    {
        _Float16* yrow = reinterpret_cast<_Float16*>(wreg + l * 144);
        f16x8 v;
        #pragma unroll
        for (int e = 0; e < 8; ++e) v[e] = idv[e];
        *reinterpret_cast<f16x8*>(&yrow[0]) = v;
        #pragma unroll
        for (int e = 0; e < 8; ++e) v[e] = idv[8 + e];
        *reinterpret_cast<f16x8*>(&yrow[8]) = v;
        #pragma unroll
        for (int e = 0; e < 8; ++e) v[e] = dxv[e];
        *reinterpret_cast<f16x8*>(&yrow[16]) = v;
        #pragma unroll
        for (int e = 0; e < 8; ++e) v[e] = dxv[8 + e];
        *reinterpret_cast<f16x8*>(&yrow[24]) = v;
        #pragma unroll
        for (int e = 0; e < 8; ++e) v[e] = dyv[e];
        *reinterpret_cast<f16x8*>(&yrow[32]) = v;
        #pragma unroll
        for (int e = 0; e < 8; ++e) v[e] = dyv[8 + e];
        *reinterpret_cast<f16x8*>(&yrow[40]) = v;
        f16x8 z;
        #pragma unroll
        for (int e = 0; e < 8; ++e) z[e] = (_Float16)0.f;
        *reinterpret_cast<f16x8*>(&yrow[48]) = z;   // K-pad 48..63 = 0
        *reinterpret_cast<f16x8*>(&yrow[56]) = z;
    }
    MEMBAR();

    // ---- Y fragments (MFMA B operand: col = pixel 16t+lr, k = 8g+j) ----
    f16x8 afrag[8];
    #pragma unroll
    for (int t = 0; t < 4; ++t)
        #pragma unroll
        for (int ks = 0; ks < 2; ++ks)
            afrag[2 * t + ks] = *reinterpret_cast<const f16x8*>(
                wreg + (16 * t + lr) * 144 + 64 * ks + 16 * g);
    MEMBAR();

    // ---- W1 fragments (A operand) ----
    f16x8 b1f[4];
    #pragma unroll
    for (int ks = 0; ks < 4; ++ks)
        b1f[ks] = *reinterpret_cast<const f16x8*>(&pw1[(ks * 64 + l) * 8]);

    f32x4 dacc[4];
    #pragma unroll
    for (int t = 0; t < 4; ++t)
        #pragma unroll
        for (int r = 0; r < 4; ++r) dacc[t][r] = 0.f;

    // ---- 4 chunks of 32 hidden: H^T = relu(W0*Y^T + b), d^T += W1*H ----
    _Float16* hb = reinterpret_cast<_Float16*>(wreg);   // [64 px][80 B] f16
    #pragma unroll
    for (int c = 0; c < 4; ++c) {
        f16x8 b0f[4];
        #pragma unroll
        for (int q = 0; q < 4; ++q)
            b0f[q] = *reinterpret_cast<const f16x8*>(&pw0[((4 * c + q) * 64 + l) * 8]);
        const f32x4 bq0 = *reinterpret_cast<const f32x4*>(&fc0_b[32 * c + 4 * g]);
        const f32x4 bq1 = *reinterpret_cast<const f32x4*>(&fc0_b[32 * c + 16 + 4 * g]);
        #pragma unroll
        for (int nl = 0; nl < 2; ++nl) {
            const f32x4 bq = nl ? bq1 : bq0;
            #pragma unroll
            for (int t = 0; t < 4; ++t) {
                f32x4 acc = {0.f, 0.f, 0.f, 0.f};
                acc = __builtin_amdgcn_mfma_f32_16x16x32_f16(b0f[2*nl+0], afrag[2*t+0], acc, 0, 0, 0);
                acc = __builtin_amdgcn_mfma_f32_16x16x32_f16(b0f[2*nl+1], afrag[2*t+1], acc, 0, 0, 0);
                // D^T: row = hidden 16nl+4g+r, col = pixel 16t+lr
                f16x4 hv;
                #pragma unroll
                for (int r = 0; r < 4; ++r)
                    hv[r] = (_Float16)fmaxf(acc[r] + bq[r], 0.f);
                *reinterpret_cast<f16x4*>(
                    reinterpret_cast<char*>(hb) + (16 * t + lr) * 80 + 32 * nl + 8 * g) = hv;
            }
        }
        MEMBAR();        // wave-private in-order DS: writes before reads
        #pragma unroll
        for (int t = 0; t < 4; ++t)
            dacc[t] = __builtin_amdgcn_mfma_f32_16x16x32_f16(
                b1f[c],
                *reinterpret_cast<const f16x8*>(
                    reinterpret_cast<const char*>(hb) + (16 * t + lr) * 80 + 16 * g),
                dacc[t], 0, 0, 0);
        MEMBAR();        // WAR before next chunk's writes
    }

    // ---- transpose d to thread-pixel layout: 4 ds_write_b128 per lane ----
    float* db = reinterpret_cast<float*>(wreg);         // [64 px][20] f32
    #pragma unroll
    for (int t = 0; t < 4; ++t)
        *reinterpret_cast<f32x4*>(&db[(16 * t + lr) * 20 + 4 * g]) = dacc[t];
    MEMBAR();

    // ---- epilogue: mask + xin re-read + paired store (rule (3), verbatim) ----
    f32x4 ov[4];
    {
        const size_t pix = ((size_t)bz * HWDIM + (y0 + i)) * HWDIM + (x0 + j);
        const float m = mask[pix];
        const float* dp = db + l * 20;
        const f32x4* xi4 = reinterpret_cast<const f32x4*>(&xin[pix * CH]);
        f32x4* xo4 = reinterpret_cast<f32x4*>(&xout[pix * CH]);
        const f32x4 dv = *reinterpret_cast<const f32x4*>(&dp[0]);
        f32x4 v0 = xi4[0];                  // ch 0..2 frozen (exact copy)
        v0[3] += dv[3] * m;
        xo4[0] = v0;
        ov[0] = v0;
        #pragma unroll
        for (int q = 1; q < 4; ++q) {
            const f32x4 d4 = *reinterpret_cast<const f32x4*>(&dp[4 * q]);
            f32x4 v = xi4[q];
            #pragma unroll
            for (int e = 0; e < 4; ++e) v[e] += d4[e] * m;
            xo4[q] = v;
            ov[q] = v;
        }
    }

    // ---- POOL (step 31 only): block-reduce channel sums -> partial;
    //      redbuf overlays the dead wave slices, LDS stays 36864 ----
    if (POOL) {
        __syncthreads();     // all waves' db reads done before redbuf overlay
        float* red = reinterpret_cast<float*>(pool);           // [256][16]
        #pragma unroll
        for (int q = 0; q < 4; ++q)
            *reinterpret_cast<f32x4*>(&red[tid * CH + 4 * q]) = ov[q];
        __syncthreads();
        for (int off = 128; off > 0; off >>= 1) {
            if (tid < off) {
                #pragma unroll
                for (int c = 0; c < CH; ++c)
                    red[tid * CH + c] += red[(tid + off) * CH + c];
            }
            __syncthreads();
        }
        if (tid < CH) {
            const int tile = (bz * 8 + blockIdx.y) * 8 + blockIdx.x;
            partial[tile * CH + tid] = red[tid];
        }
    }
}

// ---------------------------------------------------------------------------
// Classifier head, one block per batch: sum 64 tile-partials -> fc2 -> fc3.
// ---------------------------------------------------------------------------
__global__ __launch_bounds__(128) void nca_head(
    const float* __restrict__ partial,
    const float* __restrict__ fc2_w, const float* __restrict__ fc2_b,
    const float* __restrict__ fc3_w, const float* __restrict__ fc3_b,
    float* __restrict__ out)
{
    __shared__ float h2[HID];
    __shared__ float pl[CH];
    const int tid = threadIdx.x, b = blockIdx.x;
    if (tid < CH) {
        float s = 0.f;
        #pragma unroll
        for (int q = 0; q < 64; ++q) s += partial[(b * 64 + q) * CH + tid];
        pl[tid] = s * (1.f / (HWDIM * HWDIM));
    }
    __syncthreads();
    float h = fc2_b[tid];
    #pragma unroll
    for (int c = 0; c < CH; ++c) h += fc2_w[tid * CH + c] * pl[c];
    h2[tid] = fmaxf(h, 0.f);
    __syncthreads();
    if (tid < 13) {
        float o = fc3_b[tid];
        #pragma unroll
        for (int jj = 0; jj < HID; ++jj) o += fc3_w[tid * HID + jj] * h2[jj];
        out[b * 13 + tid] = o;
    }
}

// ---------------------------------------------------------------------------
extern "C" void kernel_launch(void* const* d_in, const int* in_sizes, int n_in,
                              void* d_out, int out_size, void* d_ws, size_t ws_size,
                              hipStream_t stream)
{
    const float* x     = (const float*)d_in[0];
    const float* masks = (const float*)d_in[1];
    const float* fc0_w = (const float*)d_in[2];
    const float* fc0_b = (const float*)d_in[3];
    const float* fc1_w = (const float*)d_in[4];
    const float* fc2_w = (const float*)d_in[5];
    const float* fc2_b = (const float*)d_in[6];
    const float* fc3_w = (const float*)d_in[7];
    const float* fc3_b = (const float*)d_in[8];

    float*    out     = (float*)d_out;
    float*    xf      = out + NB * 13;                             // output 1 region
    float*    buf0    = (float*)d_ws;                              // ping-pong state
    float*    partial = buf0 + (size_t)NB * HWDIM * HWDIM * CH;    // 2048*16 f
    _Float16* pw0     = (_Float16*)(partial + 2048 * CH);          // 16 KiB
    _Float16* pw1     = pw0 + 16 * 64 * 8;                         // 4 KiB

    nca_prepack<<<1, 256, 0, stream>>>(fc0_w, fc1_w, pw0, pw1);

    dim3 grid(HWDIM / 16, HWDIM / 16, NB), block(256);
    for (int s = 0; s < NSTEPS; ++s) {
        const float* in = (s == 0) ? x : ((s & 1) ? buf0 : xf);
        float* outp     = (s & 1) ? xf : buf0;
        const float* mk = masks + (size_t)s * NB * HWDIM * HWDIM;
        if (s == NSTEPS - 1)
            nca_step<true><<<grid, block, 0, stream>>>(in, outp, mk, pw0, fc0_b, pw1, partial);
        else
            nca_step<false><<<grid, block, 0, stream>>>(in, outp, mk, pw0, fc0_b, pw1, partial);
    }
    nca_head<<<NB, 128, 0, stream>>>(partial, fc2_w, fc2_b, fc3_w, fc3_b, out);
}